// Round 5
// baseline (277.441 us; speedup 1.0000x reference)
//
#include <hip/hip_runtime.h>

#define N_NODES 100000
#define N_EDGES 640000
#define D 128
#define NB ((N_NODES + 1023) / 1024)   // 98 scan blocks

typedef short v8s __attribute__((ext_vector_type(8)));
typedef float v4f __attribute__((ext_vector_type(4)));

__device__ __forceinline__ unsigned short f2bf(float x) {
    unsigned int u = __builtin_bit_cast(unsigned int, x);
    u += 0x7fffu + ((u >> 16) & 1u);   // RNE
    return (unsigned short)(u >> 16);
}
__device__ __forceinline__ float bf2f(unsigned int hi) {
    return __builtin_bit_cast(float, hi << 16);
}

// ---------------------------------------------------------------------------
// k_zero: zero pk[N] (packed deg_src lo16 | cnt_dst hi16)
// ---------------------------------------------------------------------------
__global__ __launch_bounds__(256) void k_zero(int4* __restrict__ pk4) {
    int i = blockIdx.x * blockDim.x + threadIdx.x;
    if (i < N_NODES / 4) pk4[i] = make_int4(0, 0, 0, 0);
}

// ---------------------------------------------------------------------------
// k_pre (pack + weights + bias + fused edge counting):
//   - featsh (bf16) packed into the SECOND 256B of each 512B d_out row
//   - Bcat[j][0:128]=bf16(Wm[j]), Bcat[j][128:256]=bf16(Ws[j]); bias=bm+bs
//   - first 640K threads: pk[src]+=1 (lo16), pk[dst]+=1<<16 (hi16).
//     Atomic drain overlaps the streaming pack work.
// Grid: N*(D/8) = 1.6M threads.
// ---------------------------------------------------------------------------
__global__ __launch_bounds__(256) void k_pre(const float* __restrict__ feats,
                                             const float* __restrict__ Wm,
                                             const float* __restrict__ Ws,
                                             const float* __restrict__ bmsg,
                                             const float* __restrict__ bskip,
                                             const int* __restrict__ src,
                                             const int* __restrict__ dst,
                                             unsigned int* __restrict__ pk,
                                             unsigned short* __restrict__ Bcat,
                                             float* __restrict__ bias,
                                             char* __restrict__ outb) {
    int i = blockIdx.x * blockDim.x + threadIdx.x;
    if (i < D * D) {
        int j = i >> 7;
        int k = i & 127;
        Bcat[j * 256 + k]       = f2bf(Wm[i]);
        Bcat[j * 256 + 128 + k] = f2bf(Ws[i]);
    }
    if (i < D) bias[i] = bmsg[i] + bskip[i];
    if (i < N_EDGES) {
        atomicAdd(&pk[src[i]], 1u);
        atomicAdd(&pk[dst[i]], 0x10000u);
    }
    int g = i * 8;
    int row = g >> 7;
    int col = g & 127;
    if (row < N_NODES) {
        const float4* s = (const float4*)(feats + g);
        float4 x = s[0], y = s[1];
        uint4 p;
        p.x = (unsigned)f2bf(x.x) | ((unsigned)f2bf(x.y) << 16);
        p.y = (unsigned)f2bf(x.z) | ((unsigned)f2bf(x.w) << 16);
        p.z = (unsigned)f2bf(y.x) | ((unsigned)f2bf(y.y) << 16);
        p.w = (unsigned)f2bf(y.z) | ((unsigned)f2bf(y.w) << 16);
        *(uint4*)(outb + (size_t)row * 512 + 256 + col * 2) = p;
    }
}

// ---------------------------------------------------------------------------
// Exclusive scan of cnt_dst (pk hi16) -> rowptr[N] (3 kernels)
// ---------------------------------------------------------------------------
__global__ __launch_bounds__(256) void k_scan1(const unsigned int* __restrict__ pk,
                                               int* __restrict__ rowptr,
                                               int* __restrict__ bsums) {
    __shared__ int sd[256];
    int t = threadIdx.x;
    int i0 = blockIdx.x * 1024 + t * 4;
    int v[4];
    int s = 0;
#pragma unroll
    for (int q = 0; q < 4; q++) {
        int i = i0 + q;
        v[q] = (i < N_NODES) ? (int)(pk[i] >> 16) : 0;
        s += v[q];
    }
    sd[t] = s;
    __syncthreads();
    for (int off = 1; off < 256; off <<= 1) {
        int y = (t >= off) ? sd[t - off] : 0;
        __syncthreads();
        sd[t] += y;
        __syncthreads();
    }
    int run = sd[t] - s;
    if (t == 255) bsums[blockIdx.x] = sd[255];
#pragma unroll
    for (int q = 0; q < 4; q++) {
        int i = i0 + q;
        if (i < N_NODES) rowptr[i] = run;
        run += v[q];
    }
}

__global__ __launch_bounds__(128) void k_scan2(int* __restrict__ bsums) {
    __shared__ int sd[128];
    int t = threadIdx.x;
    int v = (t < NB) ? bsums[t] : 0;
    sd[t] = v;
    __syncthreads();
    for (int off = 1; off < 128; off <<= 1) {
        int y = (t >= off) ? sd[t - off] : 0;
        __syncthreads();
        sd[t] += y;
        __syncthreads();
    }
    if (t < NB) bsums[t] = sd[t] - v;
}

// k_scan3: rowptr += block offset; dis[n] = deg_src>0 ? deg^-0.5 : 0
__global__ __launch_bounds__(256) void k_scan3(const int* __restrict__ bsums,
                                               int* __restrict__ rowptr,
                                               const unsigned int* __restrict__ pk,
                                               float* __restrict__ dis) {
    int add = bsums[blockIdx.x];
    int i0 = blockIdx.x * 1024 + threadIdx.x * 4;
#pragma unroll
    for (int q = 0; q < 4; q++) {
        int i = i0 + q;
        if (i < N_NODES) {
            rowptr[i] += add;
            int d = (int)(pk[i] & 0xffffu);
            dis[i] = (d > 0) ? (1.0f / sqrtf((float)d)) : 0.0f;
        }
    }
}

// ---------------------------------------------------------------------------
// k_fill: p = rowptr[dst]++ (atomic); csr_src[p] = src.
// rowptr mutates into end-pointers: post-fill rowptr[n] == orig rowptr[n+1].
// ---------------------------------------------------------------------------
__global__ __launch_bounds__(256) void k_fill(const int* __restrict__ src,
                                              const int* __restrict__ dst,
                                              int* __restrict__ rowptr,
                                              int* __restrict__ csr_src) {
    int e = blockIdx.x * blockDim.x + threadIdx.x;
    if (e < N_EDGES) {
        int p = atomicAdd(&rowptr[dst[e]], 1);
        csr_src[p] = src[e];
    }
}

// ---------------------------------------------------------------------------
// k_agg: one wave per node, 4 edges per iteration. Edge range for node n is
// [n==0 ? 0 : rowptr[n-1], rowptr[n]) (end-pointer CSR). Lane group g=lane>>4
// handles edge base+g; its 16 lanes each load 16B of the 256B bf16 featsh
// row. Butterfly (xor16,32) combines; group 0 writes aggh = dis[n]*sum into
// the FIRST 256B of the d_out row.
// ---------------------------------------------------------------------------
__global__ __launch_bounds__(256) void k_agg(char* __restrict__ outb,
                                             const int* __restrict__ rowptr,
                                             const int* __restrict__ csr_src,
                                             const float* __restrict__ dis) {
    int wid = (int)((blockIdx.x * (unsigned)blockDim.x + threadIdx.x) >> 6);
    int lane = threadIdx.x & 63;
    if (wid >= N_NODES) return;
    int grp = lane >> 4;
    int sub = lane & 15;
    int start = (wid == 0) ? 0 : rowptr[wid - 1];
    int end = rowptr[wid];
    float acc[8];
#pragma unroll
    for (int i = 0; i < 8; i++) acc[i] = 0.f;

    for (int base = start; base < end; base += 4) {
        int e = base + grp;
        if (e < end) {
            int s = csr_src[e];
            float sc = dis[s];
            uint4 v = *(const uint4*)(outb + (size_t)s * 512 + 256 + sub * 16);
            acc[0] += bf2f(v.x & 0xffffu) * sc;
            acc[1] += bf2f(v.x >> 16) * sc;
            acc[2] += bf2f(v.y & 0xffffu) * sc;
            acc[3] += bf2f(v.y >> 16) * sc;
            acc[4] += bf2f(v.z & 0xffffu) * sc;
            acc[5] += bf2f(v.z >> 16) * sc;
            acc[6] += bf2f(v.w & 0xffffu) * sc;
            acc[7] += bf2f(v.w >> 16) * sc;
        }
    }
#pragma unroll
    for (int i = 0; i < 8; i++) {
        acc[i] += __shfl_xor(acc[i], 16);
        acc[i] += __shfl_xor(acc[i], 32);
    }
    if (grp == 0) {
        float scn = dis[wid];
        uint4 p;
        p.x = (unsigned)f2bf(acc[0] * scn) | ((unsigned)f2bf(acc[1] * scn) << 16);
        p.y = (unsigned)f2bf(acc[2] * scn) | ((unsigned)f2bf(acc[3] * scn) << 16);
        p.z = (unsigned)f2bf(acc[4] * scn) | ((unsigned)f2bf(acc[5] * scn) << 16);
        p.w = (unsigned)f2bf(acc[6] * scn) | ((unsigned)f2bf(acc[7] * scn) << 16);
        *(uint4*)(outb + (size_t)wid * 512 + sub * 16) = p;
    }
}

// ---------------------------------------------------------------------------
// k_gemm: out[n,:] = Arow[n] @ Bcat^T + bias, MFMA 16x16x32 bf16, K=256.
// Arow = packed [aggh|featsh] bf16 rows in d_out; overwritten in place with
// the fp32 result. Block: 128 rows, 4 waves; wave = 32 rows x 128 cols.
// ---------------------------------------------------------------------------
__global__ __launch_bounds__(256) void k_gemm(const unsigned short* __restrict__ Bcat,
                                              const float* __restrict__ bias,
                                              float* __restrict__ outf) {
    __shared__ unsigned short Bl[128][264];
    const char* Ab = (const char*)outf;
    int tid = threadIdx.x;
    int lane = tid & 63;
    int w = tid >> 6;
    int n0 = blockIdx.x * 128;

    for (int i = tid; i < 128 * 32; i += 256) {
        int r = i >> 5, c = i & 31;
        *(uint4*)(&Bl[r][c * 8]) = *(const uint4*)(Bcat + r * 256 + c * 8);
    }
    __syncthreads();

    int q = lane >> 4;
    int lr = lane & 15;

    int r0 = n0 + w * 32 + lr;      if (r0 > N_NODES - 1) r0 = N_NODES - 1;
    int r1 = n0 + w * 32 + 16 + lr; if (r1 > N_NODES - 1) r1 = N_NODES - 1;
    const char* a0p = Ab + (size_t)r0 * 512 + q * 16;
    const char* a1p = Ab + (size_t)r1 * 512 + q * 16;

    v4f acc[2][8];
#pragma unroll
    for (int mt = 0; mt < 2; mt++)
#pragma unroll
        for (int t = 0; t < 8; t++) acc[mt][t] = (v4f){0.f, 0.f, 0.f, 0.f};

#pragma unroll
    for (int kk = 0; kk < 8; kk++) {
        v8s a0 = *(const v8s*)(a0p + kk * 64);
        v8s a1 = *(const v8s*)(a1p + kk * 64);
#pragma unroll
        for (int t = 0; t < 8; t++) {
            v8s b = *(const v8s*)(&Bl[t * 16 + lr][kk * 32 + q * 8]);
            acc[0][t] = __builtin_amdgcn_mfma_f32_16x16x32_bf16(a0, b, acc[0][t], 0, 0, 0);
            acc[1][t] = __builtin_amdgcn_mfma_f32_16x16x32_bf16(a1, b, acc[1][t], 0, 0, 0);
        }
    }

#pragma unroll
    for (int t = 0; t < 8; t++) {
        float bv = bias[t * 16 + lr];
#pragma unroll
        for (int mt = 0; mt < 2; mt++) {
            int rowb = n0 + w * 32 + mt * 16 + q * 4;
#pragma unroll
            for (int r = 0; r < 4; r++) {
                int row = rowb + r;
                if (row < N_NODES)
                    outf[(size_t)row * 128 + t * 16 + lr] = acc[mt][t][r] + bv;
            }
        }
    }
}

// ---------------------------------------------------------------------------
extern "C" void kernel_launch(void* const* d_in, const int* in_sizes, int n_in,
                              void* d_out, int out_size, void* d_ws, size_t ws_size,
                              hipStream_t stream) {
    const float* feats = (const float*)d_in[0];
    const int*   src   = (const int*)d_in[1];
    const int*   dst   = (const int*)d_in[2];
    const float* Wskip = (const float*)d_in[3];
    const float* bskip = (const float*)d_in[4];
    const float* Wmsg  = (const float*)d_in[5];
    const float* bmsg  = (const float*)d_in[6];

    // workspace layout:
    //   [0,       400000)   uint  pk[N]  (deg_src lo16 | cnt_dst hi16)
    //   [400000,  800000)   float dis[N]
    //   [800000, 1200128)   int   rowptr[N+1] (padded)
    //   [1200128,1200640)   int   bsums[128]
    //   [1200640,1266176)   ushort Bcat[128*256]
    //   [1266176,1266688)   float bias[128]
    //   [1266688,3826688)   int   csr_src[E]
    char* w = (char*)d_ws;
    unsigned int*   pk      = (unsigned int*)w;
    float*          dis     = (float*)(w + 400000);
    int*            rowptr  = (int*)(w + 800000);
    int*            bsums   = (int*)(w + 1200128);
    unsigned short* Bcat    = (unsigned short*)(w + 1200640);
    float*          bias    = (float*)(w + 1266176);
    int*            csr_src = (int*)(w + 1266688);

    hipLaunchKernelGGL(k_zero, dim3((N_NODES / 4 + 255) / 256), dim3(256), 0, stream,
                       (int4*)pk);
    hipLaunchKernelGGL(k_pre, dim3((N_NODES * (D / 8) + 255) / 256), dim3(256), 0,
                       stream, feats, Wmsg, Wskip, bmsg, bskip, src, dst, pk, Bcat,
                       bias, (char*)d_out);
    hipLaunchKernelGGL(k_scan1, dim3(NB), dim3(256), 0, stream, pk, rowptr, bsums);
    hipLaunchKernelGGL(k_scan2, dim3(1), dim3(128), 0, stream, bsums);
    hipLaunchKernelGGL(k_scan3, dim3(NB), dim3(256), 0, stream, bsums, rowptr,
                       pk, dis);
    hipLaunchKernelGGL(k_fill, dim3((N_EDGES + 255) / 256), dim3(256), 0, stream,
                       src, dst, rowptr, csr_src);
    hipLaunchKernelGGL(k_agg, dim3((N_NODES * 64 + 255) / 256), dim3(256), 0, stream,
                       (char*)d_out, rowptr, csr_src, dis);
    hipLaunchKernelGGL(k_gemm, dim3((N_NODES + 127) / 128), dim3(256), 0, stream,
                       Bcat, bias, (float*)d_out);
}

// Round 6
// 236.135 us; speedup vs baseline: 1.1749x; 1.1749x over previous
//
#include <hip/hip_runtime.h>

#define N_NODES 100000
#define N_EDGES 640000
#define D 128
#define NB ((N_NODES + 1023) / 1024)   // 98 scan blocks
#define BKT_C 16                        // bucket capacity: 16 ints = one 64B line
#define OVF_CAP 32768

typedef short v8s __attribute__((ext_vector_type(8)));
typedef float v4f __attribute__((ext_vector_type(4)));

__device__ __forceinline__ unsigned short f2bf(float x) {
    unsigned int u = __builtin_bit_cast(unsigned int, x);
    u += 0x7fffu + ((u >> 16) & 1u);   // RNE
    return (unsigned short)(u >> 16);
}
__device__ __forceinline__ float bf2f(unsigned int hi) {
    return __builtin_bit_cast(float, hi << 16);
}

// ---------------------------------------------------------------------------
// k_zero: zero pk[N] (deg_src lo16 | cnt_dst hi16) + ovf_cnt
// ---------------------------------------------------------------------------
__global__ __launch_bounds__(256) void k_zero(int4* __restrict__ pk4,
                                              int* __restrict__ ovf_cnt) {
    int i = blockIdx.x * blockDim.x + threadIdx.x;
    if (i < N_NODES / 4) pk4[i] = make_int4(0, 0, 0, 0);
    if (i == 0) *ovf_cnt = 0;
}

// ---------------------------------------------------------------------------
// k_pre: featsh bf16 pack into SECOND 256B of each 512B d_out row; weights ->
// Bcat bf16; bias=bm+bs; first 640K threads count degrees and (path A,
// bucket!=null) scatter src directly into per-dst 16-entry buckets
// (single-pass CSR replacement; overflow -> tiny ovf list).
// ---------------------------------------------------------------------------
__global__ __launch_bounds__(256) void k_pre(const float* __restrict__ feats,
                                             const float* __restrict__ Wm,
                                             const float* __restrict__ Ws,
                                             const float* __restrict__ bmsg,
                                             const float* __restrict__ bskip,
                                             const int* __restrict__ src,
                                             const int* __restrict__ dst,
                                             unsigned int* __restrict__ pk,
                                             unsigned short* __restrict__ Bcat,
                                             float* __restrict__ bias,
                                             char* __restrict__ outb,
                                             int* __restrict__ bucket,
                                             int* __restrict__ ovf_cnt,
                                             int2* __restrict__ ovf) {
    int i = blockIdx.x * blockDim.x + threadIdx.x;
    if (i < D * D) {
        int j = i >> 7;
        int k = i & 127;
        Bcat[j * 256 + k]       = f2bf(Wm[i]);
        Bcat[j * 256 + 128 + k] = f2bf(Ws[i]);
    }
    if (i < D) bias[i] = bmsg[i] + bskip[i];
    if (i < N_EDGES) {
        int s = src[i];
        int d = dst[i];
        atomicAdd(&pk[s], 1u);
        unsigned int old = atomicAdd(&pk[d], 0x10000u);
        if (bucket) {
            unsigned int p = old >> 16;
            if (p < BKT_C) {
                bucket[d * BKT_C + (int)p] = s;
            } else {
                int q = atomicAdd(ovf_cnt, 1);
                if (q < OVF_CAP) ovf[q] = make_int2(d, s);
            }
        }
    }
    int g = i * 8;
    int row = g >> 7;
    int col = g & 127;
    if (row < N_NODES) {
        const float4* sp = (const float4*)(feats + g);
        float4 x = sp[0], y = sp[1];
        uint4 p;
        p.x = (unsigned)f2bf(x.x) | ((unsigned)f2bf(x.y) << 16);
        p.y = (unsigned)f2bf(x.z) | ((unsigned)f2bf(x.w) << 16);
        p.z = (unsigned)f2bf(y.x) | ((unsigned)f2bf(y.y) << 16);
        p.w = (unsigned)f2bf(y.z) | ((unsigned)f2bf(y.w) << 16);
        *(uint4*)(outb + (size_t)row * 512 + 256 + col * 2) = p;
    }
}

// ---------------------------------------------------------------------------
// Path B fallback: exclusive scan of cnt_dst (pk hi16) -> rowptr, then fill.
// ---------------------------------------------------------------------------
__global__ __launch_bounds__(256) void k_scan1(const unsigned int* __restrict__ pk,
                                               int* __restrict__ rowptr,
                                               int* __restrict__ bsums) {
    __shared__ int sd[256];
    int t = threadIdx.x;
    int i0 = blockIdx.x * 1024 + t * 4;
    int v[4];
    int s = 0;
#pragma unroll
    for (int q = 0; q < 4; q++) {
        int i = i0 + q;
        v[q] = (i < N_NODES) ? (int)(pk[i] >> 16) : 0;
        s += v[q];
    }
    sd[t] = s;
    __syncthreads();
    for (int off = 1; off < 256; off <<= 1) {
        int y = (t >= off) ? sd[t - off] : 0;
        __syncthreads();
        sd[t] += y;
        __syncthreads();
    }
    int run = sd[t] - s;
    if (t == 255) bsums[blockIdx.x] = sd[255];
#pragma unroll
    for (int q = 0; q < 4; q++) {
        int i = i0 + q;
        if (i < N_NODES) rowptr[i] = run;
        run += v[q];
    }
}

__global__ __launch_bounds__(128) void k_scan2(int* __restrict__ bsums) {
    __shared__ int sd[128];
    int t = threadIdx.x;
    int v = (t < NB) ? bsums[t] : 0;
    sd[t] = v;
    __syncthreads();
    for (int off = 1; off < 128; off <<= 1) {
        int y = (t >= off) ? sd[t - off] : 0;
        __syncthreads();
        sd[t] += y;
        __syncthreads();
    }
    if (t < NB) bsums[t] = sd[t] - v;
}

__global__ __launch_bounds__(256) void k_scan3(const int* __restrict__ bsums,
                                               int* __restrict__ rowptr) {
    int add = bsums[blockIdx.x];
    int i0 = blockIdx.x * 1024 + threadIdx.x * 4;
#pragma unroll
    for (int q = 0; q < 4; q++) {
        int i = i0 + q;
        if (i < N_NODES) rowptr[i] += add;
    }
}

__global__ __launch_bounds__(256) void k_fill(const int* __restrict__ src,
                                              const int* __restrict__ dst,
                                              int* __restrict__ rowptr,
                                              int* __restrict__ csr_src) {
    int e = blockIdx.x * blockDim.x + threadIdx.x;
    if (e < N_EDGES) {
        int p = atomicAdd(&rowptr[dst[e]], 1);
        csr_src[p] = src[e];
    }
}

// ---------------------------------------------------------------------------
// Shared agg inner-body helpers: one wave per node, 4 edges/iter; lane group
// g=lane>>4 takes edge base+g; its 16 lanes load 16B of the 256B bf16 featsh
// row. sc computed on the fly: rsqrtf(deg_src) via pk lo16 (>=1 for any
// gathered src). Butterfly (xor16,32); grp 0 writes aggh = scn*sum (bf16)
// into the FIRST 256B of the d_out row.
// ---------------------------------------------------------------------------
__device__ __forceinline__ void agg_edge(const char* outb,
                                         const unsigned int* pk,
                                         int s, int sub, float* acc) {
    float sc = rsqrtf((float)(pk[s] & 0xffffu));
    uint4 v = *(const uint4*)(outb + (size_t)s * 512 + 256 + sub * 16);
    acc[0] += bf2f(v.x & 0xffffu) * sc;
    acc[1] += bf2f(v.x >> 16) * sc;
    acc[2] += bf2f(v.y & 0xffffu) * sc;
    acc[3] += bf2f(v.y >> 16) * sc;
    acc[4] += bf2f(v.z & 0xffffu) * sc;
    acc[5] += bf2f(v.z >> 16) * sc;
    acc[6] += bf2f(v.w & 0xffffu) * sc;
    acc[7] += bf2f(v.w >> 16) * sc;
}

__device__ __forceinline__ void agg_finish(char* outb, int wid,
                                           unsigned int pkn, int grp, int sub,
                                           float* acc) {
#pragma unroll
    for (int i = 0; i < 8; i++) {
        acc[i] += __shfl_xor(acc[i], 16);
        acc[i] += __shfl_xor(acc[i], 32);
    }
    if (grp == 0) {
        int dsrc = (int)(pkn & 0xffffu);
        float scn = (dsrc > 0) ? rsqrtf((float)dsrc) : 0.0f;
        uint4 p;
        p.x = (unsigned)f2bf(acc[0] * scn) | ((unsigned)f2bf(acc[1] * scn) << 16);
        p.y = (unsigned)f2bf(acc[2] * scn) | ((unsigned)f2bf(acc[3] * scn) << 16);
        p.z = (unsigned)f2bf(acc[4] * scn) | ((unsigned)f2bf(acc[5] * scn) << 16);
        p.w = (unsigned)f2bf(acc[6] * scn) | ((unsigned)f2bf(acc[7] * scn) << 16);
        *(uint4*)(outb + (size_t)wid * 512 + sub * 16) = p;
    }
}

// Path A: bucket-indexed aggregation (+ rare overflow scan)
__global__ __launch_bounds__(256) void k_agg_bkt(char* __restrict__ outb,
                                                 const unsigned int* __restrict__ pk,
                                                 const int* __restrict__ bucket,
                                                 const int* __restrict__ ovf_cnt,
                                                 const int2* __restrict__ ovf) {
    int wid = (int)((blockIdx.x * (unsigned)blockDim.x + threadIdx.x) >> 6);
    int lane = threadIdx.x & 63;
    if (wid >= N_NODES) return;
    int grp = lane >> 4;
    int sub = lane & 15;
    unsigned int pkn = pk[wid];
    int cnt = (int)(pkn >> 16);
    int m = cnt < BKT_C ? cnt : BKT_C;
    const int* bk = bucket + wid * BKT_C;
    float acc[8];
#pragma unroll
    for (int i = 0; i < 8; i++) acc[i] = 0.f;

    for (int base = 0; base < m; base += 4) {
        int e = base + grp;
        if (e < m) agg_edge(outb, pk, bk[e], sub, acc);
    }
    if (cnt > BKT_C) {   // rare (~30 nodes): scan tiny overflow list
        int no = *ovf_cnt;
        if (no > OVF_CAP) no = OVF_CAP;
        for (int i = grp; i < no; i += 4) {
            int2 p = ovf[i];
            if (p.x == wid) agg_edge(outb, pk, p.y, sub, acc);
        }
    }
    agg_finish(outb, wid, pkn, grp, sub, acc);
}

// Path B: end-pointer CSR aggregation
__global__ __launch_bounds__(256) void k_agg_csr(char* __restrict__ outb,
                                                 const unsigned int* __restrict__ pk,
                                                 const int* __restrict__ rowptr,
                                                 const int* __restrict__ csr_src) {
    int wid = (int)((blockIdx.x * (unsigned)blockDim.x + threadIdx.x) >> 6);
    int lane = threadIdx.x & 63;
    if (wid >= N_NODES) return;
    int grp = lane >> 4;
    int sub = lane & 15;
    int start = (wid == 0) ? 0 : rowptr[wid - 1];
    int end = rowptr[wid];
    float acc[8];
#pragma unroll
    for (int i = 0; i < 8; i++) acc[i] = 0.f;
    for (int base = start; base < end; base += 4) {
        int e = base + grp;
        if (e < end) agg_edge(outb, pk, csr_src[e], sub, acc);
    }
    agg_finish(outb, wid, pk[wid], grp, sub, acc);
}

// ---------------------------------------------------------------------------
// k_gemm: out[n,:] = Arow[n] @ Bcat^T + bias, MFMA 16x16x32 bf16, K=256.
// Arow = packed [aggh|featsh] bf16 rows in d_out; overwritten in place with
// the fp32 result. Block: 128 rows, 4 waves; wave = 32 rows x 128 cols.
// ---------------------------------------------------------------------------
__global__ __launch_bounds__(256) void k_gemm(const unsigned short* __restrict__ Bcat,
                                              const float* __restrict__ bias,
                                              float* __restrict__ outf) {
    __shared__ unsigned short Bl[128][264];
    const char* Ab = (const char*)outf;
    int tid = threadIdx.x;
    int lane = tid & 63;
    int w = tid >> 6;
    int n0 = blockIdx.x * 128;

    for (int i = tid; i < 128 * 32; i += 256) {
        int r = i >> 5, c = i & 31;
        *(uint4*)(&Bl[r][c * 8]) = *(const uint4*)(Bcat + r * 256 + c * 8);
    }
    __syncthreads();

    int q = lane >> 4;
    int lr = lane & 15;

    int r0 = n0 + w * 32 + lr;      if (r0 > N_NODES - 1) r0 = N_NODES - 1;
    int r1 = n0 + w * 32 + 16 + lr; if (r1 > N_NODES - 1) r1 = N_NODES - 1;
    const char* a0p = Ab + (size_t)r0 * 512 + q * 16;
    const char* a1p = Ab + (size_t)r1 * 512 + q * 16;

    v4f acc[2][8];
#pragma unroll
    for (int mt = 0; mt < 2; mt++)
#pragma unroll
        for (int t = 0; t < 8; t++) acc[mt][t] = (v4f){0.f, 0.f, 0.f, 0.f};

#pragma unroll
    for (int kk = 0; kk < 8; kk++) {
        v8s a0 = *(const v8s*)(a0p + kk * 64);
        v8s a1 = *(const v8s*)(a1p + kk * 64);
#pragma unroll
        for (int t = 0; t < 8; t++) {
            v8s b = *(const v8s*)(&Bl[t * 16 + lr][kk * 32 + q * 8]);
            acc[0][t] = __builtin_amdgcn_mfma_f32_16x16x32_bf16(a0, b, acc[0][t], 0, 0, 0);
            acc[1][t] = __builtin_amdgcn_mfma_f32_16x16x32_bf16(a1, b, acc[1][t], 0, 0, 0);
        }
    }

#pragma unroll
    for (int t = 0; t < 8; t++) {
        float bv = bias[t * 16 + lr];
#pragma unroll
        for (int mt = 0; mt < 2; mt++) {
            int rowb = n0 + w * 32 + mt * 16 + q * 4;
#pragma unroll
            for (int r = 0; r < 4; r++) {
                int row = rowb + r;
                if (row < N_NODES)
                    outf[(size_t)row * 128 + t * 16 + lr] = acc[mt][t][r] + bv;
            }
        }
    }
}

// ---------------------------------------------------------------------------
extern "C" void kernel_launch(void* const* d_in, const int* in_sizes, int n_in,
                              void* d_out, int out_size, void* d_ws, size_t ws_size,
                              hipStream_t stream) {
    const float* feats = (const float*)d_in[0];
    const int*   src   = (const int*)d_in[1];
    const int*   dst   = (const int*)d_in[2];
    const float* Wskip = (const float*)d_in[3];
    const float* bskip = (const float*)d_in[4];
    const float* Wmsg  = (const float*)d_in[5];
    const float* bmsg  = (const float*)d_in[6];

    char* w = (char*)d_ws;

    // Path A layout (single-pass bucketing), needs 7,128,320 B:
    //   [0,      400000)  uint pk[N]
    //   [400000, 400128)  int  ovf_cnt (+pad)
    //   [400128, 465664)  ushort Bcat[128*256]
    //   [465664, 466176)  float bias[128]
    //   [466176,6866176)  int  bucket[N*16]
    //   [6866176,7128320) int2 ovf[32768]
    // Path B layout (count+scan+fill), needs 3,426,688 B:
    //   [0,      400000)  uint pk[N]
    //   [400000, 800128)  int  rowptr[N+1] (+pad)
    //   [800128, 800640)  int  bsums[128]
    //   [800640, 866176)  ushort Bcat
    //   [866176, 866688)  float bias
    //   [866688,3426688)  int  csr_src[E]
    bool pathA = ws_size >= (size_t)7128320;

    if (pathA) {
        unsigned int*   pk      = (unsigned int*)w;
        int*            ovf_cnt = (int*)(w + 400000);
        unsigned short* Bcat    = (unsigned short*)(w + 400128);
        float*          bias    = (float*)(w + 465664);
        int*            bucket  = (int*)(w + 466176);
        int2*           ovf     = (int2*)(w + 6866176);

        hipLaunchKernelGGL(k_zero, dim3((N_NODES / 4 + 255) / 256), dim3(256), 0,
                           stream, (int4*)pk, ovf_cnt);
        hipLaunchKernelGGL(k_pre, dim3((N_NODES * (D / 8) + 255) / 256), dim3(256),
                           0, stream, feats, Wmsg, Wskip, bmsg, bskip, src, dst, pk,
                           Bcat, bias, (char*)d_out, bucket, ovf_cnt, ovf);
        hipLaunchKernelGGL(k_agg_bkt, dim3((N_NODES * 64 + 255) / 256), dim3(256), 0,
                           stream, (char*)d_out, pk, bucket, ovf_cnt, ovf);
        hipLaunchKernelGGL(k_gemm, dim3((N_NODES + 127) / 128), dim3(256), 0, stream,
                           Bcat, bias, (float*)d_out);
    } else {
        unsigned int*   pk      = (unsigned int*)w;
        int*            rowptr  = (int*)(w + 400000);
        int*            bsums   = (int*)(w + 800128);
        unsigned short* Bcat    = (unsigned short*)(w + 800640);
        float*          bias    = (float*)(w + 866176);
        int*            csr_src = (int*)(w + 866688);

        hipLaunchKernelGGL(k_zero, dim3((N_NODES / 4 + 255) / 256), dim3(256), 0,
                           stream, (int4*)pk, (int*)(w + 400000) /*unused slot*/);
        hipLaunchKernelGGL(k_pre, dim3((N_NODES * (D / 8) + 255) / 256), dim3(256),
                           0, stream, feats, Wmsg, Wskip, bmsg, bskip, src, dst, pk,
                           Bcat, bias, (char*)d_out, (int*)nullptr, (int*)nullptr,
                           (int2*)nullptr);
        hipLaunchKernelGGL(k_scan1, dim3(NB), dim3(256), 0, stream, pk, rowptr,
                           bsums);
        hipLaunchKernelGGL(k_scan2, dim3(1), dim3(128), 0, stream, bsums);
        hipLaunchKernelGGL(k_scan3, dim3(NB), dim3(256), 0, stream, bsums, rowptr);
        hipLaunchKernelGGL(k_fill, dim3((N_EDGES + 255) / 256), dim3(256), 0, stream,
                           src, dst, rowptr, csr_src);
        hipLaunchKernelGGL(k_agg_csr, dim3((N_NODES * 64 + 255) / 256), dim3(256), 0,
                           stream, (char*)d_out, pk, rowptr, csr_src);
        hipLaunchKernelGGL(k_gemm, dim3((N_NODES + 127) / 128), dim3(256), 0, stream,
                           Bcat, bias, (float*)d_out);
    }
}